// Round 2
// baseline (810.345 us; speedup 1.0000x reference)
//
#include <hip/hip_runtime.h>

#define M_DIM 4096
#define K_DIM 4096
#define N_DIM 11008
#define GS 128

#define BM 128
#define BN 128
#define BK 64

typedef _Float16 half8 __attribute__((ext_vector_type(8)));
typedef _Float16 half4 __attribute__((ext_vector_type(4)));
typedef _Float16 half2v __attribute__((ext_vector_type(2)));
typedef float f32x4 __attribute__((ext_vector_type(4)));

__global__ __launch_bounds__(256, 2) void gptq_gemm_kernel(
    const float* __restrict__ x,      // [M,K] fp32
    const int*   __restrict__ qw,     // [K/8, N] int32 (8 nibbles along K)
    const int*   __restrict__ qz,     // [NG, N/8] int32 (8 nibbles along N)
    const float* __restrict__ sc,     // [NG, N] fp32
    const float* __restrict__ bias,   // [N] fp32
    float* __restrict__ out)          // [M,N] fp32
{
    __shared__ _Float16 As[BM * BK];  // [m][k], XOR-swizzled
    __shared__ _Float16 Bs[BN * BK];  // [n][k], XOR-swizzled

    const int tid  = threadIdx.x;
    const int lane = tid & 63;
    const int wid  = tid >> 6;
    const int wr   = wid >> 1;   // wave row quadrant (0..1)
    const int wc   = wid & 1;    // wave col quadrant (0..1)

    // XCD-aware bijective swizzle: nwg = 32*86 = 2752 = 8*344
    const int nwg = (M_DIM / BM) * (N_DIM / BN);
    const int cpx = nwg >> 3;
    int orig = blockIdx.x;
    int wg = (orig & 7) * cpx + (orig >> 3);
    const int tiles_n = N_DIM / BN;            // 86
    const int tm = wg / tiles_n;
    const int tn = wg - tm * tiles_n;
    const int m0 = tm * BM;
    const int n0 = tn * BN;

    // ---- staging thread mapping ----
    // A: thread t loads 8x float4: row = i*16 + (t>>4), col = (t&15)*4
    const int a_r0 = tid >> 4;   // 0..15
    const int a_c4 = tid & 15;   // float4 index within BK
    // B: thread t: n_local = t&127, qweight-row parity = t>>7
    const int b_nl  = tid & 127;
    const int b_qr0 = tid >> 7;  // 0..1
    const int b_n   = n0 + b_nl;

    const float* xg  = x  + (size_t)(m0 + a_r0) * K_DIM + a_c4 * 4;
    const int*   qwg = qw + (size_t)b_qr0 * N_DIM + b_n;

    float4 areg[8];
    int    breg[4];
    float  s_cur, zs_cur;

    // prologue: load tile 0 into registers
    #pragma unroll
    for (int i = 0; i < 8; ++i)
        areg[i] = *(const float4*)(xg + (size_t)i * 16 * K_DIM);
    #pragma unroll
    for (int i = 0; i < 4; ++i)
        breg[i] = qwg[(size_t)i * 2 * N_DIM];
    {
        int zw = qz[(size_t)0 * (N_DIM / 8) + (b_n >> 3)];
        int z  = ((zw >> ((b_n & 7) * 4)) & 0xF) + 1;
        float s = sc[(size_t)0 * N_DIM + b_n];
        s_cur = s; zs_cur = -(float)z * s;
    }

    f32x4 acc[4][4];
    #pragma unroll
    for (int i = 0; i < 4; ++i)
        #pragma unroll
        for (int j = 0; j < 4; ++j)
            acc[i][j] = f32x4{0.f, 0.f, 0.f, 0.f};

    const half2v c1024 = {(_Float16)1024.0f, (_Float16)1024.0f};

    const int NK = K_DIM / BK;   // 64
    for (int kt = 0; kt < NK; ++kt) {
        if (kt) __syncthreads();     // previous tile's LDS fully consumed

        // ---- A: fp32 -> fp16, swizzled LDS write ----
        #pragma unroll
        for (int i = 0; i < 8; ++i) {
            int r = i * 16 + a_r0;
            half4 hv;
            hv[0] = (_Float16)areg[i].x; hv[1] = (_Float16)areg[i].y;
            hv[2] = (_Float16)areg[i].z; hv[3] = (_Float16)areg[i].w;
            int boff = ((r * BK + a_c4 * 4) * 2) ^ ((r & 7) << 4);
            *(half4*)((char*)As + boff) = hv;
        }

        // ---- B: int4 dequant -> fp16, swizzled LDS write ----
        {
            _Float16 sh  = (_Float16)s_cur;
            _Float16 zsh = (_Float16)zs_cur;
            half2v s2  = {sh, sh};
            half2v zs2 = {zsh, zsh};
            #pragma unroll
            for (int i = 0; i < 4; ++i) {
                unsigned q = (unsigned)breg[i];
                half2v p[4];
                #pragma unroll
                for (int j = 0; j < 4; ++j) {
                    // pair {nibble j, nibble j+4} -> exact small ints in fp16
                    unsigned t = ((q >> (4 * j)) & 0x000F000Fu) | 0x64006400u;
                    half2v h = __builtin_bit_cast(half2v, t);
                    h = h - c1024;            // exact: {q_j, q_{j+4}}
                    p[j] = h * s2 + zs2;      // (q - z) * s, packed fma
                }
                half8 wv;
                wv[0] = p[0][0]; wv[1] = p[1][0]; wv[2] = p[2][0]; wv[3] = p[3][0];
                wv[4] = p[0][1]; wv[5] = p[1][1]; wv[6] = p[2][1]; wv[7] = p[3][1];
                int qr = b_qr0 + i * 2;       // qweight row within tile (0..7)
                int boff = ((b_nl * BK + qr * 8) * 2) ^ ((b_nl & 7) << 4);
                *(half8*)((char*)Bs + boff) = wv;
            }
        }
        __syncthreads();

        // ---- prefetch next tile's globals (hide HBM latency under MFMA) ----
        if (kt + 1 < NK) {
            const float* xg2 = xg + (size_t)(kt + 1) * BK;
            #pragma unroll
            for (int i = 0; i < 8; ++i)
                areg[i] = *(const float4*)(xg2 + (size_t)i * 16 * K_DIM);
            const int* qwg2 = qwg + (size_t)(kt + 1) * (BK / 8) * N_DIM;
            #pragma unroll
            for (int i = 0; i < 4; ++i)
                breg[i] = qwg2[(size_t)i * 2 * N_DIM];
            int g  = ((kt + 1) * BK) / GS;
            int zw = qz[(size_t)g * (N_DIM / 8) + (b_n >> 3)];
            int z  = ((zw >> ((b_n & 7) * 4)) & 0xF) + 1;
            float s = sc[(size_t)g * N_DIM + b_n];
            s_cur = s; zs_cur = -(float)z * s;
        }

        // ---- MFMA on current LDS tile ----
        #pragma unroll
        for (int ks = 0; ks < 2; ++ks) {
            half8 af[4], bf[4];
            int kb = ks * 64 + ((lane >> 4) * 16);  // byte offset of this lane's 8 k's
            #pragma unroll
            for (int mi = 0; mi < 4; ++mi) {
                int r = wr * 64 + mi * 16 + (lane & 15);
                int boff = (r * (BK * 2) + kb) ^ ((r & 7) << 4);
                af[mi] = *(const half8*)((const char*)As + boff);
            }
            #pragma unroll
            for (int ni = 0; ni < 4; ++ni) {
                int c = wc * 64 + ni * 16 + (lane & 15);
                int boff = (c * (BK * 2) + kb) ^ ((c & 7) << 4);
                bf[ni] = *(const half8*)((const char*)Bs + boff);
            }
            #pragma unroll
            for (int mi = 0; mi < 4; ++mi)
                #pragma unroll
                for (int ni = 0; ni < 4; ++ni)
                    acc[mi][ni] = __builtin_amdgcn_mfma_f32_16x16x32_f16(
                        af[mi], bf[ni], acc[mi][ni], 0, 0, 0);
        }
    }

    // ---- epilogue: +bias, fp32 store ----
    const int col_base = n0 + wc * 64 + (lane & 15);
    const int row_base = m0 + wr * 64 + ((lane >> 4) << 2);
    #pragma unroll
    for (int ni = 0; ni < 4; ++ni) {
        int col = col_base + ni * 16;
        float bv = bias[col];
        #pragma unroll
        for (int mi = 0; mi < 4; ++mi) {
            int row = row_base + mi * 16;
            #pragma unroll
            for (int j = 0; j < 4; ++j)
                out[(size_t)(row + j) * N_DIM + col] = acc[mi][ni][j] + bv;
        }
    }
}

extern "C" void kernel_launch(void* const* d_in, const int* in_sizes, int n_in,
                              void* d_out, int out_size, void* d_ws, size_t ws_size,
                              hipStream_t stream) {
    const float* x    = (const float*)d_in[0];
    const int*   qw   = (const int*)d_in[1];
    const int*   qz   = (const int*)d_in[2];
    const float* sc   = (const float*)d_in[3];
    // d_in[4] = g_idx (== arange(K)//GS, recomputed on the fly)
    const float* bias = (const float*)d_in[5];
    float* out = (float*)d_out;

    const int grid = (M_DIM / BM) * (N_DIM / BN);  // 2752
    gptq_gemm_kernel<<<grid, 256, 0, stream>>>(x, qw, qz, sc, bias, out);
}

// Round 4
// 631.953 us; speedup vs baseline: 1.2823x; 1.2823x over previous
//
#include <hip/hip_runtime.h>

#define M_DIM 4096
#define K_DIM 4096
#define N_DIM 11008
#define GS 128
#define NT 128            // K-tiles of 32

typedef _Float16 half8 __attribute__((ext_vector_type(8)));
typedef _Float16 half4 __attribute__((ext_vector_type(4)));
typedef _Float16 half2v __attribute__((ext_vector_type(2)));
typedef float f32x4 __attribute__((ext_vector_type(4)));

#define AH_BYTES 33554432ull              // 4096*4096*2
#define WT_BYTES 90177536ull              // 11008*4096*2

// ================= prepass A: fp32 -> fp16 (linear) =================
__global__ __launch_bounds__(256) void cvtA_kernel(const float4* __restrict__ x4,
                                                   half8* __restrict__ a8) {
    int i = blockIdx.x * 256 + threadIdx.x;
    float4 u = x4[2 * i];
    float4 v = x4[2 * i + 1];
    half8 h;
    h[0] = (_Float16)u.x; h[1] = (_Float16)u.y; h[2] = (_Float16)u.z; h[3] = (_Float16)u.w;
    h[4] = (_Float16)v.x; h[5] = (_Float16)v.y; h[6] = (_Float16)v.z; h[7] = (_Float16)v.w;
    a8[i] = h;
}

// ======== prepass W: int4 dequant + transpose -> Wt[N][K] fp16 ========
__global__ __launch_bounds__(256) void dequantW_kernel(const int* __restrict__ qw,
                                                       const int* __restrict__ qz,
                                                       const float* __restrict__ sc,
                                                       _Float16* __restrict__ Wt) {
    // tile: 64 k  x 64 n.  grid = (K/64) * (N/64) = 64 * 172
    const int tk = blockIdx.x & 63;
    const int tn = blockIdx.x >> 6;
    const int k0 = tk * 64, n0 = tn * 64;
    const int g = k0 >> 7;                 // one group per tile (64 | 128)

    __shared__ _Float16 Lt[64][65];        // [k][n], +1 pad

    const int t = threadIdx.x;
    const int n = t & 63;
    const int kwh = t >> 6;                // 0..3
    const int gn = n0 + n;

    float s = sc[(size_t)g * N_DIM + gn];
    int zw = qz[(size_t)g * (N_DIM / 8) + (gn >> 3)];
    int z = ((zw >> ((gn & 7) * 4)) & 0xF) + 1;
    _Float16 sh = (_Float16)s;
    _Float16 zsh = (_Float16)(-(float)z * s);
    half2v s2 = {sh, sh}, zs2 = {zsh, zsh};
    const half2v c1024 = {(_Float16)1024.0f, (_Float16)1024.0f};

    #pragma unroll
    for (int j = 0; j < 2; ++j) {
        int kw = j * 4 + kwh;              // word-row within tile (0..7)
        unsigned q = (unsigned)qw[(size_t)(tk * 8 + kw) * N_DIM + gn];
        half2v p[4];
        #pragma unroll
        for (int jj = 0; jj < 4; ++jj) {
            unsigned tt = ((q >> (4 * jj)) & 0x000F000Fu) | 0x64006400u;
            half2v h = __builtin_bit_cast(half2v, tt);
            h = h - c1024;                 // exact {nib jj, nib jj+4}
            p[jj] = h * s2 + zs2;          // (q - z) * s
        }
        int kr = kw * 8;
        Lt[kr + 0][n] = p[0][0]; Lt[kr + 1][n] = p[1][0];
        Lt[kr + 2][n] = p[2][0]; Lt[kr + 3][n] = p[3][0];
        Lt[kr + 4][n] = p[0][1]; Lt[kr + 5][n] = p[1][1];
        Lt[kr + 6][n] = p[2][1]; Lt[kr + 7][n] = p[3][1];
    }
    __syncthreads();

    // transposed write: thread -> (n_l, c): 32B of k
    const int n_l = t >> 2;
    const int c = t & 3;
    half8 o0, o1;
    #pragma unroll
    for (int jj = 0; jj < 8; ++jj) {
        o0[jj] = Lt[c * 16 + jj][n_l];
        o1[jj] = Lt[c * 16 + 8 + jj][n_l];
    }
    size_t base = (size_t)(n0 + n_l) * K_DIM + k0 + c * 16;
    *(half8*)(Wt + base) = o0;
    *(half8*)(Wt + base + 8) = o1;
}

// ================= main GEMM: 256x256 tile, BK=32, 4-buffer ring =================
// LDS per buffer: A 256x32 fp16 (16KB) + B 256x32 fp16 (16KB) = 32KB; 4 bufs = 128KB.
// Row stride 64B. Swizzle: byte-slot kb ^= ((r>>1)&3)<<4  (2-way = free on frag reads).

#define SWZ(r) ((((r) >> 1) & 3) << 4)

#define VMC8() asm volatile("s_waitcnt vmcnt(8)" ::: "memory")
#define VMC4() asm volatile("s_waitcnt vmcnt(4)" ::: "memory")
#define VMC0() asm volatile("s_waitcnt vmcnt(0)" ::: "memory")
#define VMCN()

// stage one unit (A or B, 16KB) of tile TILE into its ring slot
#define STAGE(TILE, UNIT) do {                                                        \
    char* db_ = smem + ((TILE) & 3) * 32768 + ((UNIT) * 16384);                       \
    const char* gb_ = (UNIT) ? wtb : ahb;                                             \
    size_t o0_ = ((UNIT) ? srcB0 : srcA0) + (size_t)(TILE) * 64;                      \
    size_t o1_ = ((UNIT) ? srcB1 : srcA1) + (size_t)(TILE) * 64;                      \
    __builtin_amdgcn_global_load_lds(                                                 \
        (const __attribute__((address_space(1))) void*)(gb_ + o0_),                   \
        (__attribute__((address_space(3))) void*)(db_ + e0 * 1024), 16, 0, 0);        \
    __builtin_amdgcn_global_load_lds(                                                 \
        (const __attribute__((address_space(1))) void*)(gb_ + o1_),                   \
        (__attribute__((address_space(3))) void*)(db_ + e1 * 1024), 16, 0, 0);        \
} while (0)

#define PHASE(CT, MH, STG, VMC) do {                                                  \
    const int cb_ = (CT) & 3;                                                         \
    const char* Ab_ = smem + cb_ * 32768;                                             \
    const char* Bb_ = Ab_ + 16384;                                                    \
    half8 af0 = *(const half8*)(Ab_ + aoff##MH##_0);                                  \
    half8 af1 = *(const half8*)(Ab_ + aoff##MH##_1);                                  \
    half8 af2 = *(const half8*)(Ab_ + aoff##MH##_2);                                  \
    half8 af3 = *(const half8*)(Ab_ + aoff##MH##_3);                                  \
    half8 bf0 = *(const half8*)(Bb_ + boff_0);                                        \
    half8 bf1 = *(const half8*)(Bb_ + boff_1);                                        \
    half8 bf2 = *(const half8*)(Bb_ + boff_2);                                        \
    half8 bf3 = *(const half8*)(Bb_ + boff_3);                                        \
    if (STG) { STAGE((CT) + 3, MH); }                                                 \
    VMC();                                                                            \
    __builtin_amdgcn_s_barrier();                                                     \
    asm volatile("s_waitcnt lgkmcnt(0)" ::: "memory");                                \
    __builtin_amdgcn_sched_barrier(0);                                                \
    __builtin_amdgcn_s_setprio(1);                                                    \
    acc[(MH)*4+0][0] = __builtin_amdgcn_mfma_f32_16x16x32_f16(af0, bf0, acc[(MH)*4+0][0], 0, 0, 0); \
    acc[(MH)*4+0][1] = __builtin_amdgcn_mfma_f32_16x16x32_f16(af0, bf1, acc[(MH)*4+0][1], 0, 0, 0); \
    acc[(MH)*4+0][2] = __builtin_amdgcn_mfma_f32_16x16x32_f16(af0, bf2, acc[(MH)*4+0][2], 0, 0, 0); \
    acc[(MH)*4+0][3] = __builtin_amdgcn_mfma_f32_16x16x32_f16(af0, bf3, acc[(MH)*4+0][3], 0, 0, 0); \
    acc[(MH)*4+1][0] = __builtin_amdgcn_mfma_f32_16x16x32_f16(af1, bf0, acc[(MH)*4+1][0], 0, 0, 0); \
    acc[(MH)*4+1][1] = __builtin_amdgcn_mfma_f32_16x16x32_f16(af1, bf1, acc[(MH)*4+1][1], 0, 0, 0); \
    acc[(MH)*4+1][2] = __builtin_amdgcn_mfma_f32_16x16x32_f16(af1, bf2, acc[(MH)*4+1][2], 0, 0, 0); \
    acc[(MH)*4+1][3] = __builtin_amdgcn_mfma_f32_16x16x32_f16(af1, bf3, acc[(MH)*4+1][3], 0, 0, 0); \
    acc[(MH)*4+2][0] = __builtin_amdgcn_mfma_f32_16x16x32_f16(af2, bf0, acc[(MH)*4+2][0], 0, 0, 0); \
    acc[(MH)*4+2][1] = __builtin_amdgcn_mfma_f32_16x16x32_f16(af2, bf1, acc[(MH)*4+2][1], 0, 0, 0); \
    acc[(MH)*4+2][2] = __builtin_amdgcn_mfma_f32_16x16x32_f16(af2, bf2, acc[(MH)*4+2][2], 0, 0, 0); \
    acc[(MH)*4+2][3] = __builtin_amdgcn_mfma_f32_16x16x32_f16(af2, bf3, acc[(MH)*4+2][3], 0, 0, 0); \
    acc[(MH)*4+3][0] = __builtin_amdgcn_mfma_f32_16x16x32_f16(af3, bf0, acc[(MH)*4+3][0], 0, 0, 0); \
    acc[(MH)*4+3][1] = __builtin_amdgcn_mfma_f32_16x16x32_f16(af3, bf1, acc[(MH)*4+3][1], 0, 0, 0); \
    acc[(MH)*4+3][2] = __builtin_amdgcn_mfma_f32_16x16x32_f16(af3, bf2, acc[(MH)*4+3][2], 0, 0, 0); \
    acc[(MH)*4+3][3] = __builtin_amdgcn_mfma_f32_16x16x32_f16(af3, bf3, acc[(MH)*4+3][3], 0, 0, 0); \
    __builtin_amdgcn_s_setprio(0);                                                    \
    __builtin_amdgcn_s_barrier();                                                     \
} while (0)

__global__ __launch_bounds__(512, 2) void gemm8_kernel(
    const _Float16* __restrict__ Ah,   // [M][K] fp16
    const _Float16* __restrict__ Wt,   // [N][K] fp16
    const float* __restrict__ bias,    // [N]
    float* __restrict__ out)           // [M][N] fp32
{
    extern __shared__ char smem[];     // 131072 B

    const int tid  = threadIdx.x;
    const int lane = tid & 63;
    const int wid  = tid >> 6;         // 0..7
    const int wr   = wid >> 2;         // 0..1 (128 rows each)
    const int wc   = wid & 3;          // 0..3 (64 cols each)

    // XCD-aware bijective swizzle: nwg = 16*43 = 688 = 8*86
    int orig = blockIdx.x;
    int wg = (orig & 7) * 86 + (orig >> 3);
    const int tm = wg / 43;
    const int tn = wg - tm * 43;
    const int m0 = tm * 256;
    const int n0 = tn * 256;

    const char* ahb = (const char*)Ah;
    const char* wtb = (const char*)Wt;

    // ---- staging addresses (per thread) ----
    const int e0 = wid, e1 = wid + 8;                  // 1KB issues per unit
    const int r0 = e0 * 16 + (lane >> 2);              // tile-local row
    const int r1 = e1 * 16 + (lane >> 2);
    const int kb0 = ((lane & 3) << 4) ^ SWZ(r0);       // inverse-swizzled source k-bytes
    const int kb1 = ((lane & 3) << 4) ^ SWZ(r1);
    const size_t srcA0 = ((size_t)(m0 + r0) << 13) + kb0;   // row * 8192B
    const size_t srcA1 = ((size_t)(m0 + r1) << 13) + kb1;
    const size_t srcB0 = ((size_t)(n0 + r0) << 13) + kb0;
    const size_t srcB1 = ((size_t)(n0 + r1) << 13) + kb1;

    // ---- fragment LDS byte offsets (loop-invariant, swizzled) ----
    const int kbr = (lane >> 4) << 4;
    int ra, aoff0_0, aoff0_1, aoff0_2, aoff0_3, aoff1_0, aoff1_1, aoff1_2, aoff1_3;
    ra = wr * 128 +   0 + (lane & 15); aoff0_0 = ra * 64 + (kbr ^ SWZ(ra));
    ra = wr * 128 +  16 + (lane & 15); aoff0_1 = ra * 64 + (kbr ^ SWZ(ra));
    ra = wr * 128 +  32 + (lane & 15); aoff0_2 = ra * 64 + (kbr ^ SWZ(ra));
    ra = wr * 128 +  48 + (lane & 15); aoff0_3 = ra * 64 + (kbr ^ SWZ(ra));
    ra = wr * 128 +  64 + (lane & 15); aoff1_0 = ra * 64 + (kbr ^ SWZ(ra));
    ra = wr * 128 +  80 + (lane & 15); aoff1_1 = ra * 64 + (kbr ^ SWZ(ra));
    ra = wr * 128 +  96 + (lane & 15); aoff1_2 = ra * 64 + (kbr ^ SWZ(ra));
    ra = wr * 128 + 112 + (lane & 15); aoff1_3 = ra * 64 + (kbr ^ SWZ(ra));
    int boff_0, boff_1, boff_2, boff_3;
    ra = wc * 64 +  0 + (lane & 15); boff_0 = ra * 64 + (kbr ^ SWZ(ra));
    ra = wc * 64 + 16 + (lane & 15); boff_1 = ra * 64 + (kbr ^ SWZ(ra));
    ra = wc * 64 + 32 + (lane & 15); boff_2 = ra * 64 + (kbr ^ SWZ(ra));
    ra = wc * 64 + 48 + (lane & 15); boff_3 = ra * 64 + (kbr ^ SWZ(ra));

    f32x4 acc[8][4];
    #pragma unroll
    for (int i = 0; i < 8; ++i)
        #pragma unroll
        for (int j = 0; j < 4; ++j)
            acc[i][j] = f32x4{0.f, 0.f, 0.f, 0.f};

    // ---- prologue: tiles 0,1,2 in flight; confirm tile 0 ----
    STAGE(0, 0); STAGE(0, 1);
    STAGE(1, 0); STAGE(1, 1);
    STAGE(2, 0); STAGE(2, 1);
    VMC8();                           // retire A0,B0
    __builtin_amdgcn_s_barrier();

    // ---- main loop: iters 0..30 compute tiles 0..123 ----
    for (int i = 0; i < 31; ++i) {
        const int T = 4 * i;
        PHASE(T + 0, 0, 1, VMCN);     // stage A(T+3)
        PHASE(T + 0, 1, 1, VMC8);     // stage B(T+3); confirm tile T+1
        PHASE(T + 1, 0, 1, VMCN);     // stage A(T+4)
        PHASE(T + 1, 1, 1, VMC8);     // confirm tile T+2
        PHASE(T + 2, 0, 1, VMCN);     // stage A(T+5)
        PHASE(T + 2, 1, 1, VMC8);     // confirm tile T+3
        PHASE(T + 3, 0, 1, VMCN);     // stage A(T+6)
        PHASE(T + 3, 1, 1, VMC8);     // confirm tile T+4
    }
    // ---- peeled last iteration: tiles 124..127, drain 8 -> 4 -> 0 ----
    PHASE(124, 0, 1, VMCN);           // stage A(127)
    PHASE(124, 1, 1, VMC8);           // stage B(127); confirm 125
    PHASE(125, 0, 0, VMCN);
    PHASE(125, 1, 0, VMC4);           // confirm 126
    PHASE(126, 0, 0, VMCN);
    PHASE(126, 1, 0, VMC0);           // confirm 127
    PHASE(127, 0, 0, VMCN);
    PHASE(127, 1, 0, VMCN);

    // ---- epilogue: + bias, fp32 store ----
    const int row_base = m0 + wr * 128 + ((lane >> 4) << 2);
    const int col_base = n0 + wc * 64 + (lane & 15);
    #pragma unroll
    for (int ni = 0; ni < 4; ++ni) {
        const int col = col_base + ni * 16;
        const float bv = bias[col];
        #pragma unroll
        for (int mi = 0; mi < 8; ++mi) {
            const int row = row_base + mi * 16;
            #pragma unroll
            for (int j = 0; j < 4; ++j)
                out[(size_t)(row + j) * N_DIM + col] = acc[mi][ni][j] + bv;
        }
    }
}

// ================= fallback (round-2 kernel, used if ws too small) =================
__global__ __launch_bounds__(256, 2) void gptq_fallback_kernel(
    const float* __restrict__ x, const int* __restrict__ qw, const int* __restrict__ qz,
    const float* __restrict__ sc, const float* __restrict__ bias, float* __restrict__ out)
{
    __shared__ _Float16 As[128 * 64];
    __shared__ _Float16 Bs[128 * 64];
    const int tid = threadIdx.x, lane = tid & 63, wid = tid >> 6;
    const int wr = wid >> 1, wc = wid & 1;
    int orig = blockIdx.x;
    int wg = (orig & 7) * 344 + (orig >> 3);
    const int tm = wg / 86, tn = wg - tm * 86;
    const int m0 = tm * 128, n0 = tn * 128;
    const int a_r0 = tid >> 4, a_c4 = tid & 15;
    const int b_nl = tid & 127, b_qr0 = tid >> 7, b_n = n0 + b_nl;
    const float* xg = x + (size_t)(m0 + a_r0) * K_DIM + a_c4 * 4;
    const int* qwg = qw + (size_t)b_qr0 * N_DIM + b_n;
    float4 areg[8]; int breg[4]; float s_cur, zs_cur;
    #pragma unroll
    for (int i = 0; i < 8; ++i) areg[i] = *(const float4*)(xg + (size_t)i * 16 * K_DIM);
    #pragma unroll
    for (int i = 0; i < 4; ++i) breg[i] = qwg[(size_t)i * 2 * N_DIM];
    { int zw = qz[(size_t)(b_n >> 3)]; int z = ((zw >> ((b_n & 7) * 4)) & 0xF) + 1;
      float s = sc[b_n]; s_cur = s; zs_cur = -(float)z * s; }
    f32x4 acc[4][4];
    #pragma unroll
    for (int i = 0; i < 4; ++i)
        #pragma unroll
        for (int j = 0; j < 4; ++j) acc[i][j] = f32x4{0.f,0.f,0.f,0.f};
    const half2v c1024 = {(_Float16)1024.0f, (_Float16)1024.0f};
    for (int kt = 0; kt < 64; ++kt) {
        if (kt) __syncthreads();
        #pragma unroll
        for (int i = 0; i < 8; ++i) {
            int r = i * 16 + a_r0;
            half4 hv; hv[0]=(_Float16)areg[i].x; hv[1]=(_Float16)areg[i].y;
            hv[2]=(_Float16)areg[i].z; hv[3]=(_Float16)areg[i].w;
            int boff = ((r * 64 + a_c4 * 4) * 2) ^ ((r & 7) << 4);
            *(half4*)((char*)As + boff) = hv;
        }
        { _Float16 sh=(_Float16)s_cur, zsh=(_Float16)zs_cur;
          half2v s2={sh,sh}, zs2={zsh,zsh};
          #pragma unroll
          for (int i = 0; i < 4; ++i) {
            unsigned q = (unsigned)breg[i]; half2v p[4];
            #pragma unroll
            for (int j = 0; j < 4; ++j) {
                unsigned t = ((q >> (4*j)) & 0x000F000Fu) | 0x64006400u;
                half2v h = __builtin_bit_cast(half2v, t); h = h - c1024;
                p[j] = h * s2 + zs2;
            }
            half8 wv; wv[0]=p[0][0]; wv[1]=p[1][0]; wv[2]=p[2][0]; wv[3]=p[3][0];
            wv[4]=p[0][1]; wv[5]=p[1][1]; wv[6]=p[2][1]; wv[7]=p[3][1];
            int qr = b_qr0 + i * 2;
            int boff = ((b_nl * 64 + qr * 8) * 2) ^ ((b_nl & 7) << 4);
            *(half8*)((char*)Bs + boff) = wv;
          } }
        __syncthreads();
        if (kt + 1 < 64) {
            const float* xg2 = xg + (size_t)(kt + 1) * 64;
            #pragma unroll
            for (int i = 0; i < 8; ++i) areg[i] = *(const float4*)(xg2 + (size_t)i * 16 * K_DIM);
            const int* qwg2 = qwg + (size_t)(kt + 1) * 8 * N_DIM;
            #pragma unroll
            for (int i = 0; i < 4; ++i) breg[i] = qwg2[(size_t)i * 2 * N_DIM];
            int g = ((kt + 1) * 64) / GS;
            int zw = qz[(size_t)g * (N_DIM / 8) + (b_n >> 3)];
            int z = ((zw >> ((b_n & 7) * 4)) & 0xF) + 1;
            float s = sc[(size_t)g * N_DIM + b_n];
            s_cur = s; zs_cur = -(float)z * s;
        }
        #pragma unroll
        for (int ks = 0; ks < 2; ++ks) {
            half8 af[4], bf[4];
            int kb = ks * 64 + ((lane >> 4) * 16);
            #pragma unroll
            for (int mi = 0; mi < 4; ++mi) {
                int r = wr * 64 + mi * 16 + (lane & 15);
                int boff = (r * 128 + kb) ^ ((r & 7) << 4);
                af[mi] = *(const half8*)((const char*)As + boff);
            }
            #pragma unroll
            for (int ni = 0; ni < 4; ++ni) {
                int c = wc * 64 + ni * 16 + (lane & 15);
                int boff = (c * 128 + kb) ^ ((c & 7) << 4);
                bf[ni] = *(const half8*)((const char*)Bs + boff);
            }
            #pragma unroll
            for (int mi = 0; mi < 4; ++mi)
                #pragma unroll
                for (int ni = 0; ni < 4; ++ni)
                    acc[mi][ni] = __builtin_amdgcn_mfma_f32_16x16x32_f16(af[mi], bf[ni], acc[mi][ni], 0, 0, 0);
        }
    }
    const int col_base = n0 + wc * 64 + (lane & 15);
    const int row_base = m0 + wr * 64 + ((lane >> 4) << 2);
    #pragma unroll
    for (int ni = 0; ni < 4; ++ni) {
        int col = col_base + ni * 16;
        float bv = bias[col];
        #pragma unroll
        for (int mi = 0; mi < 4; ++mi) {
            int row = row_base + mi * 16;
            #pragma unroll
            for (int j = 0; j < 4; ++j)
                out[(size_t)(row + j) * N_DIM + col] = acc[mi][ni][j] + bv;
        }
    }
}

extern "C" void kernel_launch(void* const* d_in, const int* in_sizes, int n_in,
                              void* d_out, int out_size, void* d_ws, size_t ws_size,
                              hipStream_t stream) {
    const float* x    = (const float*)d_in[0];
    const int*   qw   = (const int*)d_in[1];
    const int*   qz   = (const int*)d_in[2];
    const float* sc   = (const float*)d_in[3];
    const float* bias = (const float*)d_in[5];
    float* out = (float*)d_out;

    if (ws_size >= AH_BYTES + WT_BYTES) {
        _Float16* Ah = (_Float16*)d_ws;
        _Float16* Wt = (_Float16*)((char*)d_ws + AH_BYTES);
        cvtA_kernel<<<8192, 256, 0, stream>>>((const float4*)x, (half8*)Ah);
        dequantW_kernel<<<64 * 172, 256, 0, stream>>>(qw, qz, sc, Wt);
        (void)hipFuncSetAttribute((const void*)gemm8_kernel,
                                  hipFuncAttributeMaxDynamicSharedMemorySize, 131072);
        gemm8_kernel<<<688, 512, 131072, stream>>>(Ah, Wt, bias, out);
    } else {
        gptq_fallback_kernel<<<2752, 256, 0, stream>>>(x, qw, qz, sc, bias, out);
    }
}